// Round 1
// baseline (471.217 us; speedup 1.0000x reference)
//
#include <hip/hip_runtime.h>

namespace {

constexpr int S    = 384;
constexpr int D    = 64;
constexpr int QT   = 64;       // q-rows per block
constexpr int KC   = 96;       // V k-chunk staged per barrier
constexpr int NCH  = S / KC;   // 4 chunks
constexpr int PROW = 384;      // shorts per P_lds row (swizzled, no pad)
constexpr int VROW = 128;      // shorts per Vt_lds row (16 x 16B groups)

typedef float        f32x2 __attribute__((ext_vector_type(2)));
typedef float        f32x4 __attribute__((ext_vector_type(4)));
typedef unsigned int u32x4 __attribute__((ext_vector_type(4)));
typedef __bf16       bf16x8 __attribute__((ext_vector_type(8)));

__device__ __forceinline__ unsigned int f2bf(float f) {
    // round-to-nearest-even fp32 -> bf16 (inputs here are finite)
    unsigned int u = __float_as_uint(f);
    u += 0x7fffu + ((u >> 16) & 1u);
    return u >> 16;
}

__global__ __launch_bounds__(256, 2)
void softmax_drop_pv(const float* __restrict__ scores,
                     const float* __restrict__ vmat,
                     const float* __restrict__ dmask,
                     float* __restrict__ out)
{
    // 49152 + 16384 = 65536 B -> 2 blocks/CU on 160 KiB LDS
    __shared__ alignas(16) unsigned short P_lds[QT * PROW];
    __shared__ alignas(16) unsigned short Vt_lds[D * VROW];

    const int tid  = threadIdx.x;
    const int lane = tid & 63;
    const int wave = tid >> 6;
    const int bh   = blockIdx.x / (S / QT);
    const int q0   = (blockIdx.x % (S / QT)) * QT;

    unsigned int* P32 = reinterpret_cast<unsigned int*>(P_lds);
    const size_t rb0 = ((size_t)bh * S + q0) * S;

    // ---------------- Phase 0: softmax + dropout -> bf16 P in LDS ----------
    // Each wave owns 16 q-rows; lane holds k = 2*lane + 128*j (j=0..2) pairs.
    for (int r = 0; r < QT / 4; ++r) {
        const int q = wave * (QT / 4) + r;
        const f32x2* srow =
            reinterpret_cast<const f32x2*>(scores + rb0 + (size_t)q * S) + lane;
        const f32x2* mrow =
            reinterpret_cast<const f32x2*>(dmask + rb0 + (size_t)q * S) + lane;
        f32x2 s0 = __builtin_nontemporal_load(srow);
        f32x2 s1 = __builtin_nontemporal_load(srow + 64);
        f32x2 s2 = __builtin_nontemporal_load(srow + 128);
        f32x2 m0 = __builtin_nontemporal_load(mrow);
        f32x2 m1 = __builtin_nontemporal_load(mrow + 64);
        f32x2 m2 = __builtin_nontemporal_load(mrow + 128);

        float mx = fmaxf(fmaxf(fmaxf(s0.x, s0.y), fmaxf(s1.x, s1.y)),
                         fmaxf(s2.x, s2.y));
#pragma unroll
        for (int i = 32; i >= 1; i >>= 1) mx = fmaxf(mx, __shfl_xor(mx, i, 64));

        float e0 = __expf(s0.x - mx), e1 = __expf(s0.y - mx);
        float e2 = __expf(s1.x - mx), e3 = __expf(s1.y - mx);
        float e4 = __expf(s2.x - mx), e5 = __expf(s2.y - mx);
        float l = ((e0 + e1) + (e2 + e3)) + (e4 + e5);
#pragma unroll
        for (int i = 32; i >= 1; i >>= 1) l += __shfl_xor(l, i, 64);
        const float inv = 1.0f / l;   // softmax denom uses ALL k (mask after)

        unsigned int w0 = f2bf(e0 * m0.x * inv) | (f2bf(e1 * m0.y * inv) << 16);
        unsigned int w1 = f2bf(e2 * m1.x * inv) | (f2bf(e3 * m1.y * inv) << 16);
        unsigned int w2 = f2bf(e4 * m2.x * inv) | (f2bf(e5 * m2.y * inv) << 16);

        // dword column c in row; 16B k-group = c>>2; swizzle group ^= (q&7)
        unsigned int* prow = P32 + q * (PROW / 2);
        const int x4 = (q & 7) << 2;
        const int c0 = lane, c1 = lane + 64, c2 = lane + 128;
        prow[((c0 & ~3) ^ x4) | (c0 & 3)] = w0;
        prow[((c1 & ~3) ^ x4) | (c1 & 3)] = w1;
        prow[((c2 & ~3) ^ x4) | (c2 & 3)] = w2;
    }

    // ---------------- Phase 1: P @ V via bf16 MFMA --------------------------
    f32x4 acc[4] = {};

    for (int ch = 0; ch < NCH; ++ch) {
        if (ch > 0) __syncthreads();   // prior chunk's mfma reads done
        // stage V chunk -> Vt_lds (transposed [d][k], bf16, XOR-swizzled)
#pragma unroll
        for (int ii = 0; ii < KC / 32; ++ii) {   // 3 iters
            const int kg = ii * 4 + wave;        // chunk-local k-group (8 k's)
            const float* vp =
                vmat + ((size_t)bh * S + ch * KC + kg * 8) * D + lane;
            float v0 = vp[0 * D], v1 = vp[1 * D], v2 = vp[2 * D], v3 = vp[3 * D];
            float v4 = vp[4 * D], v5 = vp[5 * D], v6 = vp[6 * D], v7 = vp[7 * D];
            u32x4 pk;
            pk.x = f2bf(v0) | (f2bf(v1) << 16);
            pk.y = f2bf(v2) | (f2bf(v3) << 16);
            pk.z = f2bf(v4) | (f2bf(v5) << 16);
            pk.w = f2bf(v6) | (f2bf(v7) << 16);
            *reinterpret_cast<u32x4*>(
                &Vt_lds[lane * VROW + ((kg ^ (lane & 7)) << 3)]) = pk;
        }
        __syncthreads();

        const int quad = lane >> 4;
        const int qrow = wave * 16 + (lane & 15);   // own wave's P rows only
        const int qx   = qrow & 7;
#pragma unroll
        for (int s = 0; s < KC / 32; ++s) {
            const int kgG = ch * (KC / 8) + s * 4 + quad;  // global P k-group
            bf16x8 a = *reinterpret_cast<const bf16x8*>(
                &P_lds[qrow * PROW + ((kgG ^ qx) << 3)]);
            const int kgl = s * 4 + quad;                  // chunk-local group
#pragma unroll
            for (int t = 0; t < 4; ++t) {
                const int dcol = t * 16 + (lane & 15);
                bf16x8 b = *reinterpret_cast<const bf16x8*>(
                    &Vt_lds[dcol * VROW + ((kgl ^ (dcol & 7)) << 3)]);
                acc[t] = __builtin_amdgcn_mfma_f32_16x16x32_bf16(a, b, acc[t],
                                                                 0, 0, 0);
            }
        }
    }

    // ---------------- Epilogue: store fp32 out ------------------------------
    // C/D layout (m89-verified): col = lane&15, row = (lane>>4)*4 + reg
    const size_t ob   = ((size_t)bh * S + q0) * D;
    const int    orow = wave * 16 + ((lane >> 4) << 2);
    const int    ocol = lane & 15;
#pragma unroll
    for (int t = 0; t < 4; ++t) {
#pragma unroll
        for (int r = 0; r < 4; ++r) {
            __builtin_nontemporal_store(
                acc[t][r], out + ob + (size_t)(orow + r) * D + (t * 16 + ocol));
        }
    }
}

} // namespace

extern "C" void kernel_launch(void* const* d_in, const int* in_sizes, int n_in,
                              void* d_out, int out_size, void* d_ws, size_t ws_size,
                              hipStream_t stream)
{
    const float* scores = (const float*)d_in[0];  // x429 [B,H,S,S]
    const float* vmat   = (const float*)d_in[1];  // x419 [B,H,S,D]
    const float* dmask  = (const float*)d_in[2];  // dropout_mask [B,H,S,S]
    float* out = (float*)d_out;                   // [B,H,S,D] fp32

    const int BH = 32 * 12;
    dim3 grid(BH * (S / QT));   // 2304 blocks
    dim3 block(256);
    softmax_drop_pv<<<grid, block, 0, stream>>>(scores, vmat, dmask, out);
}

// Round 2
// 452.019 us; speedup vs baseline: 1.0425x; 1.0425x over previous
//
#include <hip/hip_runtime.h>

namespace {

constexpr int S    = 384;
constexpr int D    = 64;
constexpr int QT   = 64;        // q-rows per block
constexpr int KC   = 64;        // V k-chunk per stage
constexpr int NCH  = S / KC;    // 6
constexpr int PROW = 384;       // shorts per P_lds row (48 x 16B groups)
constexpr int VROW = 64;        // shorts per Vt row per buffer (8 x 16B groups)

typedef float        f32x4  __attribute__((ext_vector_type(4)));
typedef unsigned int u32x2  __attribute__((ext_vector_type(2)));
typedef unsigned int u32x4  __attribute__((ext_vector_type(4)));
typedef __bf16       bf16x8 __attribute__((ext_vector_type(8)));

__device__ __forceinline__ unsigned int f2bf(float f) {
    // round-to-nearest-even fp32 -> bf16 (finite inputs)
    unsigned int u = __float_as_uint(f);
    u += 0x7fffu + ((u >> 16) & 1u);
    return u >> 16;
}

__global__ __launch_bounds__(256, 2)
void softmax_drop_pv(const float* __restrict__ scores,
                     const float* __restrict__ vmat,
                     const float* __restrict__ dmask,
                     float* __restrict__ out)
{
    // 49152 + 16384 + 256 = 65792 B -> 2 blocks/CU (160 KiB LDS)
    __shared__ alignas(16) unsigned short P_lds[QT * PROW];
    __shared__ alignas(16) unsigned short Vt_lds[2][D * VROW];
    __shared__ float linv[QT];

    const int tid  = threadIdx.x;
    const int lane = tid & 63;
    const int wave = tid >> 6;
    const int rh   = lane >> 5;   // half-wave id: which row of the pair
    const int l32  = lane & 31;
    const int bh   = blockIdx.x / (S / QT);
    const int q0   = (blockIdx.x % (S / QT)) * QT;
    const size_t rb0 = ((size_t)bh * S + q0) * S;

    unsigned int* P32 = reinterpret_cast<unsigned int*>(P_lds);

    // ------------- Phase 0: softmax*mask -> bf16 P (unnormalized) -----------
    // Each half-wave owns one q-row per iteration; lane loads 3 float4s.
    f32x4 sv[2][3], mv[2][3];
    auto issue = [&](int i, int sl) {
        const int row = wave * 16 + 2 * i + rh;
        const f32x4* sp =
            reinterpret_cast<const f32x4*>(scores + rb0 + (size_t)row * S) + l32;
        const f32x4* mp =
            reinterpret_cast<const f32x4*>(dmask  + rb0 + (size_t)row * S) + l32;
        sv[sl][0] = __builtin_nontemporal_load(sp);
        sv[sl][1] = __builtin_nontemporal_load(sp + 32);
        sv[sl][2] = __builtin_nontemporal_load(sp + 64);
        mv[sl][0] = __builtin_nontemporal_load(mp);
        mv[sl][1] = __builtin_nontemporal_load(mp + 32);
        mv[sl][2] = __builtin_nontemporal_load(mp + 64);
    };

    issue(0, 0);
#pragma unroll
    for (int i = 0; i < 8; ++i) {
        const int cur = i & 1;
        if (i < 7) issue(i + 1, cur ^ 1);   // prefetch next row pair

        const int row = wave * 16 + 2 * i + rh;
        const f32x4 s0 = sv[cur][0], s1 = sv[cur][1], s2 = sv[cur][2];
        const f32x4 m0 = mv[cur][0], m1 = mv[cur][1], m2 = mv[cur][2];

        float mx = fmaxf(fmaxf(fmaxf(s0.x, s0.y), fmaxf(s0.z, s0.w)),
                   fmaxf(fmaxf(fmaxf(s1.x, s1.y), fmaxf(s1.z, s1.w)),
                         fmaxf(fmaxf(s2.x, s2.y), fmaxf(s2.z, s2.w))));
#pragma unroll
        for (int d = 16; d >= 1; d >>= 1)   // stays within 32-lane half
            mx = fmaxf(mx, __shfl_xor(mx, d, 64));

        const float e0  = __expf(s0.x - mx), e1  = __expf(s0.y - mx);
        const float e2  = __expf(s0.z - mx), e3  = __expf(s0.w - mx);
        const float e4  = __expf(s1.x - mx), e5  = __expf(s1.y - mx);
        const float e6  = __expf(s1.z - mx), e7  = __expf(s1.w - mx);
        const float e8  = __expf(s2.x - mx), e9  = __expf(s2.y - mx);
        const float e10 = __expf(s2.z - mx), e11 = __expf(s2.w - mx);

        float l = (((e0 + e1) + (e2 + e3)) + ((e4 + e5) + (e6 + e7))) +
                  ((e8 + e9) + (e10 + e11));
#pragma unroll
        for (int d = 16; d >= 1; d >>= 1)
            l += __shfl_xor(l, d, 64);
        if (l32 == 0) linv[row] = 1.0f / l;   // normalization deferred

        u32x2 w0, w1, w2;   // p = exp * mask, packed bf16 (unnormalized)
        w0.x = f2bf(e0  * m0.x) | (f2bf(e1  * m0.y) << 16);
        w0.y = f2bf(e2  * m0.z) | (f2bf(e3  * m0.w) << 16);
        w1.x = f2bf(e4  * m1.x) | (f2bf(e5  * m1.y) << 16);
        w1.y = f2bf(e6  * m1.z) | (f2bf(e7  * m1.w) << 16);
        w2.x = f2bf(e8  * m2.x) | (f2bf(e9  * m2.y) << 16);
        w2.y = f2bf(e10 * m2.z) | (f2bf(e11 * m2.w) << 16);

        // 16B k-group g = j*16 + (l32>>1); octet-XOR swizzle by (row&7)
        const int xsw = row & 7;
        const int gb  = l32 >> 1;
        unsigned int* prow =
            P32 + row * (PROW / 2) + ((gb ^ xsw) << 2) + ((l32 & 1) << 1);
        *reinterpret_cast<u32x2*>(prow)       = w0;
        *reinterpret_cast<u32x2*>(prow + 64)  = w1;
        *reinterpret_cast<u32x2*>(prow + 128) = w2;
    }

    // ------------- Phase 1: P @ V via bf16 MFMA, dbuf V staging -------------
    auto stage = [&](int ch, int buf) {
#pragma unroll
        for (int ii = 0; ii < 2; ++ii) {
            const int kg = ii * 4 + wave;   // chunk-local k-group (8 k's)
            const float* vp =
                vmat + ((size_t)bh * S + ch * KC + kg * 8) * D + lane;
            const float v0 = vp[0 * D], v1 = vp[1 * D];
            const float v2 = vp[2 * D], v3 = vp[3 * D];
            const float v4 = vp[4 * D], v5 = vp[5 * D];
            const float v6 = vp[6 * D], v7 = vp[7 * D];
            u32x4 pk;
            pk.x = f2bf(v0) | (f2bf(v1) << 16);
            pk.y = f2bf(v2) | (f2bf(v3) << 16);
            pk.z = f2bf(v4) | (f2bf(v5) << 16);
            pk.w = f2bf(v6) | (f2bf(v7) << 16);
            *reinterpret_cast<u32x4*>(
                &Vt_lds[buf][lane * VROW + ((kg ^ (lane & 7)) << 3)]) = pk;
        }
    };

    f32x4 acc[4] = {};
    const int quad  = lane >> 4;
    const int qrow  = wave * 16 + (lane & 15);
    const int qx    = qrow & 7;
    const int dbase = lane & 15;

    stage(0, 0);
    __syncthreads();   // covers phase-0 P writes, linv, and chunk-0 V stage

#pragma unroll
    for (int ch = 0; ch < NCH; ++ch) {
        if (ch < NCH - 1) stage(ch + 1, (ch + 1) & 1);   // overlap with MFMA
#pragma unroll
        for (int s = 0; s < 2; ++s) {
            const int kgG = ch * 8 + s * 4 + quad;       // global P k-group
            const bf16x8 a = *reinterpret_cast<const bf16x8*>(
                &P_lds[qrow * PROW + ((kgG ^ qx) << 3)]);
            const int kgl = s * 4 + quad;                // chunk-local group
#pragma unroll
            for (int t = 0; t < 4; ++t) {
                const int dcol = t * 16 + dbase;
                const bf16x8 b = *reinterpret_cast<const bf16x8*>(
                    &Vt_lds[ch & 1][dcol * VROW + ((kgl ^ (dcol & 7)) << 3)]);
                acc[t] = __builtin_amdgcn_mfma_f32_16x16x32_bf16(a, b, acc[t],
                                                                 0, 0, 0);
            }
        }
        if (ch < NCH - 1) __syncthreads();
    }

    // ------------- Epilogue: scale by 1/l, store fp32 -----------------------
    // C/D layout (m89-verified): col = lane&15, row = (lane>>4)*4 + reg
    const size_t ob   = ((size_t)bh * S + q0) * D;
    const int    orow = wave * 16 + (quad << 2);
    const int    ocol = dbase;
    float iv[4];
#pragma unroll
    for (int r = 0; r < 4; ++r) iv[r] = linv[orow + r];
#pragma unroll
    for (int t = 0; t < 4; ++t) {
#pragma unroll
        for (int r = 0; r < 4; ++r) {
            __builtin_nontemporal_store(
                acc[t][r] * iv[r],
                out + ob + (size_t)(orow + r) * D + (t * 16 + ocol));
        }
    }
}

} // namespace

extern "C" void kernel_launch(void* const* d_in, const int* in_sizes, int n_in,
                              void* d_out, int out_size, void* d_ws, size_t ws_size,
                              hipStream_t stream)
{
    const float* scores = (const float*)d_in[0];  // x429 [B,H,S,S]
    const float* vmat   = (const float*)d_in[1];  // x419 [B,H,S,D]
    const float* dmask  = (const float*)d_in[2];  // dropout_mask [B,H,S,S]
    float* out = (float*)d_out;                   // [B,H,S,D] fp32

    const int BH = 32 * 12;
    dim3 grid(BH * (S / QT));   // 2304 blocks
    dim3 block(256);
    softmax_drop_pv<<<grid, block, 0, stream>>>(scores, vmat, dmask, out);
}